// Round 1
// 700.925 us; speedup vs baseline: 1.0082x; 1.0082x over previous
//
#include <hip/hip_runtime.h>
#include <math.h>

#define B_ 8
#define N_ 4096
#define D_ 768
#define H_ 8
#define HD_ 96
#define FG_ 2049
#define TWO_PI 6.283185307179586476925f
// LDS anti-bank-conflict padding: one extra slot per 32
#define PAD(i) ((i) + ((i) >> 5))

__device__ __forceinline__ float gelu_f(float x) {
    return 0.5f * x * (1.0f + erff(x * 0.7071067811865475f));
}

__global__ void k_zero(float* p, int n) {
    int i = blockIdx.x * 256 + threadIdx.x;
    if (i < n) p[i] = 0.f;
}

// One-time tables: twiddle W[k] = exp(-2*pi*i*k/4096) (float2), Hann(4096).
__global__ void k_tables(float2* __restrict__ twg, float* __restrict__ hanng) {
    int i = blockIdx.x * 256 + threadIdx.x;
    if (i < 2048) {
        float s, c;
        sincosf(-TWO_PI * (float)i / 4096.0f, &s, &c);
        twg[i] = make_float2(c, s);
    }
    if (i < 4096) hanng[i] = 0.5f - 0.5f * cosf(TWO_PI * (float)i / 4095.0f);
}

// Wave-per-row LayerNorm stats: mu, rstd per (b,n) row. 4 waves/block.
__global__ __launch_bounds__(256) void k_stats(const float* __restrict__ x,
                                               float* __restrict__ mu,
                                               float* __restrict__ rstd) {
    int row = blockIdx.x * 4 + (threadIdx.x >> 6);
    int lane = threadIdx.x & 63;
    const float4* xr = (const float4*)(x + (size_t)row * D_);
    float4 a = xr[lane], b = xr[lane + 64], c = xr[lane + 128];
    float s = a.x + a.y + a.z + a.w + b.x + b.y + b.z + b.w + c.x + c.y + c.z + c.w;
    #pragma unroll
    for (int o = 32; o > 0; o >>= 1) s += __shfl_xor(s, o);
    float m = s * (1.0f / 768.0f);
    float v = 0.f, d;
    d = a.x - m; v += d * d; d = a.y - m; v += d * d;
    d = a.z - m; v += d * d; d = a.w - m; v += d * d;
    d = b.x - m; v += d * d; d = b.y - m; v += d * d;
    d = b.z - m; v += d * d; d = b.w - m; v += d * d;
    d = c.x - m; v += d * d; d = c.y - m; v += d * d;
    d = c.z - m; v += d * d; d = c.w - m; v += d * d;
    #pragma unroll
    for (int o = 32; o > 0; o >>= 1) v += __shfl_xor(v, o);
    if (lane == 0) {
        mu[row] = m;
        rstd[row] = rsqrtf(v * (1.0f / 768.0f) + 1e-5f);
    }
}

// Fused: normalize + transposed write [B][D][N] + ctx partial sums (atomics).
__global__ __launch_bounds__(256) void k_lnT(const float* __restrict__ x,
                                             const float* __restrict__ mu,
                                             const float* __restrict__ rstd,
                                             const float* __restrict__ lw,
                                             const float* __restrict__ lb,
                                             float* __restrict__ xt,
                                             float* __restrict__ ctx) {
    __shared__ float tile[64][65];
    __shared__ float csum[4][64];
    int d0 = blockIdx.x * 64, n0 = blockIdx.y * 64, b = blockIdx.z;
    int c = threadIdx.x & 63, r4 = threadIdx.x >> 6;
    float w = lw[d0 + c], bias = lb[d0 + c];
    float partial = 0.f;
    #pragma unroll
    for (int q = 0; q < 16; ++q) {
        int r = r4 * 16 + q;
        int row = b * N_ + n0 + r;
        float v = (x[(size_t)row * D_ + d0 + c] - mu[row]) * rstd[row] * w + bias;
        tile[r][c] = v;
        partial += v;
    }
    csum[r4][c] = partial;
    __syncthreads();
    if (r4 == 0)
        atomicAdd(ctx + b * D_ + d0 + c,
                  (csum[0][c] + csum[1][c] + csum[2][c] + csum[3][c]) * (1.0f / 4096.0f));
    #pragma unroll
    for (int q = 0; q < 16; ++q) {
        int r = r4 * 16 + q;  // d-row
        xt[((size_t)b * D_ + d0 + r) * N_ + n0 + c] = tile[c][r];
    }
}

// h1g = gelu(ctx@w1g+b1g), h1l = gelu(ctx@w1l+b1l), hf = gelu(ctx@wf1+bf1)
__global__ void k_mlp1(const float* __restrict__ ctx,
                       const float* __restrict__ w1g, const float* __restrict__ b1g,
                       const float* __restrict__ w1l, const float* __restrict__ b1l,
                       const float* __restrict__ wf1, const float* __restrict__ bf1,
                       float* __restrict__ h1g, float* __restrict__ h1l, float* __restrict__ hf) {
    __shared__ float cl[B_ * D_];
    for (int i = threadIdx.x; i < B_ * D_; i += 256) cl[i] = ctx[i];
    __syncthreads();
    int c = blockIdx.x * 256 + threadIdx.x;
    if (c >= 1920) return;
    const float *w, *bias; float* out; int ncol, cc;
    if (c < 768)      { w = w1g; bias = b1g; out = h1g; ncol = 768; cc = c; }
    else if (c < 1536){ w = w1l; bias = b1l; out = h1l; ncol = 768; cc = c - 768; }
    else              { w = wf1; bias = bf1; out = hf;  ncol = 384; cc = c - 1536; }
    float acc[B_];
    #pragma unroll
    for (int b = 0; b < B_; ++b) acc[b] = 0.f;
    for (int d = 0; d < 768; ++d) {
        float wv = w[(size_t)d * ncol + cc];
        #pragma unroll
        for (int b = 0; b < B_; ++b) acc[b] += cl[b * 768 + d] * wv;
    }
    float bv = bias[cc];
    for (int b = 0; b < B_; ++b) out[b * ncol + cc] = gelu_f(acc[b] + bv);
}

// ag[b,c] = b2g[c]; al[b,c] = b2l[c]  (bias init for split-K accumulation)
__global__ void k_biasinit(const float* __restrict__ b2g, const float* __restrict__ b2l,
                           float* __restrict__ ag, float* __restrict__ al) {
    int c = blockIdx.x * 256 + threadIdx.x;
    const int CG = H_ * FG_ * 2;  // 32784
    if (c < CG) {
        float v = b2g[c];
        for (int b = 0; b < B_; ++b) ag[(size_t)b * CG + c] = v;
    } else if (c < CG + 80) {
        int cc = c - CG;
        float v = b2l[cc];
        for (int b = 0; b < B_; ++b) al[b * 80 + cc] = v;
    }
}

// split-K (8 chunks of 96): ag += h1g@w2g chunk; al += h1l@w2l chunk; gate full.
__global__ void k_mlp2(const float* __restrict__ h1g, const float* __restrict__ h1l,
                       const float* __restrict__ hf,
                       const float* __restrict__ w2g, const float* __restrict__ w2l,
                       const float* __restrict__ wf2, const float* __restrict__ bf2,
                       float* __restrict__ ag, float* __restrict__ al, float* __restrict__ gate) {
    int kc = blockIdx.y;       // 0..7
    int d0 = kc * 96;
    __shared__ float lg[B_ * 96];
    __shared__ float ll[B_ * 96];
    for (int i = threadIdx.x; i < B_ * 96; i += 256) {
        int bb = i / 96, dd = i % 96;
        lg[i] = h1g[bb * 768 + d0 + dd];
        ll[i] = h1l[bb * 768 + d0 + dd];
    }
    __syncthreads();
    int c = blockIdx.x * 256 + threadIdx.x;
    const int CG = H_ * FG_ * 2;  // 32784
    float acc[B_];
    #pragma unroll
    for (int b = 0; b < B_; ++b) acc[b] = 0.f;
    if (c < CG) {
        for (int d = 0; d < 96; ++d) {
            float wv = w2g[(size_t)(d0 + d) * CG + c];
            #pragma unroll
            for (int b = 0; b < B_; ++b) acc[b] += lg[b * 96 + d] * wv;
        }
        for (int b = 0; b < B_; ++b) atomicAdd(ag + (size_t)b * CG + c, acc[b]);
    } else if (c < CG + 80) {
        int cc = c - CG;
        for (int d = 0; d < 96; ++d) {
            float wv = w2l[(d0 + d) * 80 + cc];
            #pragma unroll
            for (int b = 0; b < B_; ++b) acc[b] += ll[b * 96 + d] * wv;
        }
        for (int b = 0; b < B_; ++b) atomicAdd(al + b * 80 + cc, acc[b]);
    } else if (c < CG + 88 && kc == 0) {
        int cc = c - CG - 80;
        for (int d = 0; d < 384; ++d) {
            float wv = wf2[d * 8 + cc];
            #pragma unroll
            for (int b = 0; b < B_; ++b) acc[b] += hf[b * 384 + d] * wv;
        }
        for (int b = 0; b < B_; ++b)
            gate[b * 8 + cc] = 1.0f / (1.0f + expf(-(acc[b] + bf2[cc])));
    }
}

// One FFT pass: stages 1-4 in registers (per-thread 16-element block,
// constant W16 twiddles), stages 5-12 in LDS (float2, b64 accesses).
__device__ __forceinline__ void fft_pass(float2* z, const float2* tw4,
                                         const float2* __restrict__ twg,
                                         int t, float sign) {
    float2 v[16];
    #pragma unroll
    for (int i = 0; i < 16; ++i) v[i] = z[PAD(t * 16 + i)];
    const float TC[8] = {1.f, 0.92387953251f, 0.70710678119f, 0.38268343236f,
                         0.f, -0.38268343236f, -0.70710678119f, -0.92387953251f};
    const float TS[8] = {0.f, -0.38268343236f, -0.70710678119f, -0.92387953251f,
                         -1.f, -0.92387953251f, -0.70710678119f, -0.38268343236f};
    #pragma unroll
    for (int s = 1; s <= 4; ++s) {
        int half = 1 << (s - 1);
        #pragma unroll
        for (int u = 0; u < 8; ++u) {
            int lg = u >> (s - 1), pos = u & (half - 1);
            int i1 = (lg << s) + pos, i2 = i1 + half;
            int m = pos << (4 - s);
            float wr = TC[m], wi = sign * TS[m];
            float2 a = v[i1], bb = v[i2];
            float tr = bb.x * wr - bb.y * wi;
            float ti = bb.x * wi + bb.y * wr;
            v[i1] = make_float2(a.x + tr, a.y + ti);
            v[i2] = make_float2(a.x - tr, a.y - ti);
        }
    }
    #pragma unroll
    for (int i = 0; i < 16; ++i) z[PAD(t * 16 + i)] = v[i];
    __syncthreads();
    // stages 5..10: twiddles from LDS tw4 (W^(4m))
    for (int s = 5; s <= 10; ++s) {
        int half = 1 << (s - 1);
        int sh = 12 - s;
        #pragma unroll
        for (int u = 0; u < 8; ++u) {
            int j = t + (u << 8);
            int grp = j >> (s - 1);
            int pos = j & (half - 1);
            int i1 = (grp << s) + pos;
            int p1 = PAD(i1), p2 = PAD(i1 + half);
            float2 w = tw4[PAD(pos << (sh - 2))];
            float wi = sign * w.y;
            float2 a = z[p1], bb = z[p2];
            float tr = bb.x * w.x - bb.y * wi;
            float ti = bb.x * wi + bb.y * w.x;
            z[p1] = make_float2(a.x + tr, a.y + ti);
            z[p2] = make_float2(a.x - tr, a.y - ti);
        }
        __syncthreads();
    }
    // stages 11..12: twiddles straight from global (L1-resident 16KB table)
    for (int s = 11; s <= 12; ++s) {
        int half = 1 << (s - 1);
        int sh = 12 - s;
        #pragma unroll
        for (int u = 0; u < 8; ++u) {
            int j = t + (u << 8);
            int grp = j >> (s - 1);
            int pos = j & (half - 1);
            int i1 = (grp << s) + pos;
            int p1 = PAD(i1), p2 = PAD(i1 + half);
            float2 w = twg[pos << sh];
            float wi = sign * w.y;
            float2 a = z[p1], bb = z[p2];
            float tr = bb.x * w.x - bb.y * wi;
            float ti = bb.x * wi + bb.y * w.x;
            z[p1] = make_float2(a.x + tr, a.y + ti);
            z[p2] = make_float2(a.x - tr, a.y - ti);
        }
        __syncthreads();
    }
}

// One block per PAIR of lines (2m, 2m+1): packed complex FFT does both.
__global__ __launch_bounds__(256, 4) void k_spectral(
        const float* __restrict__ xt,    // [B][D][N]
        const float* __restrict__ ag,    // [B][32784]
        const float* __restrict__ al,    // [B][80]
        const float* __restrict__ gate,  // [B][8]
        const float* __restrict__ bf_g, const float* __restrict__ bb_g,
        const float* __restrict__ bf_l, const float* __restrict__ bb_l,
        const float2* __restrict__ twg, const float* __restrict__ hanng,
        float* __restrict__ fused)       // [B][D][N]
{
    __shared__ float2 z[4224];
    __shared__ float2 tw4[528];   // W^(4m), m<512, padded
    int line0 = blockIdx.x * 2;   // b*768 + d0, d0 even
    int d0 = line0 % 768, b = line0 / 768;
    int h = d0 / HD_;             // both lines share h (HD=96 even)
    int t = threadIdx.x;

    for (int m = t; m < 512; m += 256) tw4[PAD(m)] = twg[4 * m];

    // load both raw lines (16 contiguous n per thread each)
    const float* src0 = xt + (size_t)line0 * N_;
    const float* src1 = src0 + N_;
    float raw0[16], raw1[16];
    #pragma unroll
    for (int q = 0; q < 4; ++q) {
        float4 v0 = ((const float4*)src0)[t * 4 + q];
        float4 v1 = ((const float4*)src1)[t * 4 + q];
        raw0[q * 4 + 0] = v0.x; raw0[q * 4 + 1] = v0.y;
        raw0[q * 4 + 2] = v0.z; raw0[q * 4 + 3] = v0.w;
        raw1[q * 4 + 0] = v1.x; raw1[q * 4 + 1] = v1.y;
        raw1[q * 4 + 2] = v1.z; raw1[q * 4 + 3] = v1.w;
    }
    // deposit packed complex z = x0 + i*x1, Hann-windowed, bit-reversed
    #pragma unroll
    for (int q = 0; q < 4; ++q) {
        float4 hw = ((const float4*)hanng)[t * 4 + q];
        int nb = t * 16 + q * 4;
        int r0 = PAD((int)(__brev((unsigned)(nb + 0)) >> 20));
        int r1 = PAD((int)(__brev((unsigned)(nb + 1)) >> 20));
        int r2 = PAD((int)(__brev((unsigned)(nb + 2)) >> 20));
        int r3 = PAD((int)(__brev((unsigned)(nb + 3)) >> 20));
        z[r0] = make_float2(raw0[q * 4 + 0] * hw.x, raw1[q * 4 + 0] * hw.x);
        z[r1] = make_float2(raw0[q * 4 + 1] * hw.y, raw1[q * 4 + 1] * hw.y);
        z[r2] = make_float2(raw0[q * 4 + 2] * hw.z, raw1[q * 4 + 2] * hw.z);
        z[r3] = make_float2(raw0[q * 4 + 3] * hw.w, raw1[q * 4 + 3] * hw.w);
    }

    // ---- local branch in registers (2 windows of 8 per thread, both lines) ----
    float alc = gate[b * 8 + h];
    const float* alb = al + b * 80;
    float effl_f[5], effl_b[5];
    #pragma unroll
    for (int f = 0; f < 5; ++f) {
        int idx = h * 5 + f;
        effl_f[f] = bf_l[idx] * (1.0f + alb[idx * 2]);
        effl_b[f] = bb_l[idx] + alb[idx * 2 + 1];
    }
    const float s8 = 0.3535533905932738f;  // 1/sqrt(8)
    const float c7 = 0.7071067811865476f;
    const float cosT[8] = {1.f, c7, 0.f, -c7, -1.f, -c7, 0.f, c7};
    const float sinT[8] = {0.f, c7, 1.f, c7, 0.f, -c7, -1.f, -c7};
    const float hl[8] = {0.f, 0.18825510f, 0.61126047f, 0.95048444f,
                         0.95048444f, 0.61126047f, 0.18825510f, 0.f};
    float xl0[16], xl1[16];
    #pragma unroll
    for (int ln = 0; ln < 2; ++ln) {
        float* rawp = ln ? raw1 : raw0;
        float* xlp  = ln ? xl1 : xl0;
        #pragma unroll
        for (int w2 = 0; w2 < 2; ++w2) {
            float xw[8];
            #pragma unroll
            for (int j = 0; j < 8; ++j) xw[j] = rawp[w2 * 8 + j] * hl[j];
            float Yr[5], Yi[5];
            #pragma unroll
            for (int f = 0; f < 5; ++f) {
                float fr = 0.f, fi = 0.f;
                #pragma unroll
                for (int j = 0; j < 8; ++j) {
                    int k8 = (f * j) & 7;
                    fr += xw[j] * cosT[k8];
                    fi -= xw[j] * sinT[k8];
                }
                fr *= s8; fi *= s8;
                float zr = fr * effl_f[f] + effl_b[f];
                float zi = fi * effl_f[f];
                float mag = sqrtf(zr * zr + zi * zi);
                float g = gelu_f(mag) / (mag + 1e-6f);
                Yr[f] = zr * g; Yi[f] = zi * g;
            }
            #pragma unroll
            for (int j = 0; j < 8; ++j) {
                float acc = Yr[0] + Yr[4] * ((j & 1) ? -1.f : 1.f);
                #pragma unroll
                for (int f = 1; f < 4; ++f) {
                    int k8 = (f * j) & 7;
                    acc += 2.f * (Yr[f] * cosT[k8] - Yi[f] * sinT[k8]);
                }
                xlp[w2 * 8 + j] = acc * s8;
            }
        }
    }

    __syncthreads();
    // forward FFT: Z = FFT(x0 + i*x1), natural order out
    fft_pass(z, tw4, twg, t, 1.0f);

    // Hermitian split + modulate + cgelu + re-pack (in place; thread owns {k, 4096-k})
    const float inv64 = 1.0f / 64.0f;
    const float* agb = ag + (size_t)b * 32784;
    for (int k = t; k < 2048; k += 256) {
        int km = (4096 - k) & 4095;
        int pk = PAD(k), pm = PAD(km);
        float2 Z = z[pk], Z2 = z[pm];
        float X0r = 0.5f * (Z.x + Z2.x), X0i = 0.5f * (Z.y - Z2.y);
        float X1r = 0.5f * (Z.y + Z2.y), X1i = -0.5f * (Z.x - Z2.x);
        int idx = h * FG_ + k;
        float efff = bf_g[idx] * (1.0f + agb[idx * 2]);
        float effb = bb_g[idx] + agb[idx * 2 + 1];
        float z0r = X0r * inv64 * efff + effb, z0i = X0i * inv64 * efff;
        float m0 = sqrtf(z0r * z0r + z0i * z0i);
        float g0 = gelu_f(m0) / (m0 + 1e-6f);
        float Y0r = z0r * g0, Y0i = z0i * g0;
        float z1r = X1r * inv64 * efff + effb, z1i = X1i * inv64 * efff;
        float m1 = sqrtf(z1r * z1r + z1i * z1i);
        float g1 = gelu_f(m1) / (m1 + 1e-6f);
        float Y1r = z1r * g1, Y1i = z1i * g1;
        z[pk] = make_float2(Y0r - Y1i, Y0i + Y1r);
        if (k) z[pm] = make_float2(Y0r + Y1i, Y1r - Y0i);
    }
    if (t == 0) {  // Nyquist bin k=2048 (self-mirror; X0,X1 real)
        int pk = PAD(2048);
        float2 Z = z[pk];
        int idx = h * FG_ + 2048;
        float efff = bf_g[idx] * (1.0f + agb[idx * 2]);
        float effb = bb_g[idx] + agb[idx * 2 + 1];
        float z0r = Z.x * inv64 * efff + effb;
        float m0 = fabsf(z0r);
        float Y0r = z0r * (gelu_f(m0) / (m0 + 1e-6f));
        float z1r = Z.y * inv64 * efff + effb;
        float m1 = fabsf(z1r);
        float Y1r = z1r * (gelu_f(m1) / (m1 + 1e-6f));
        z[pk] = make_float2(Y0r, Y1r);
    }
    __syncthreads();
    // bit-reverse permutation (padded)
    for (int n = t; n < 4096; n += 256) {
        int r = (int)(__brev((unsigned)n) >> 20);
        if (r > n) {
            int pn = PAD(n), pr = PAD(r);
            float2 a = z[pn]; z[pn] = z[pr]; z[pr] = a;
        }
    }
    __syncthreads();
    // inverse FFT: w = N*IDFT(P); y0 = Re(w)/64, y1 = Im(w)/64
    fft_pass(z, tw4, twg, t, -1.0f);

    // fuse and store both lines
    float* dst0 = fused + (size_t)line0 * N_;
    float* dst1 = dst0 + N_;
    float one_m = 1.0f - alc;
    #pragma unroll
    for (int q = 0; q < 4; ++q) {
        int base = t * 16 + q * 4;
        float2 za = z[PAD(base + 0)], zb = z[PAD(base + 1)];
        float2 zc = z[PAD(base + 2)], zd = z[PAD(base + 3)];
        float4 v0 = make_float4(alc * za.x * inv64 + one_m * xl0[q * 4 + 0],
                                alc * zb.x * inv64 + one_m * xl0[q * 4 + 1],
                                alc * zc.x * inv64 + one_m * xl0[q * 4 + 2],
                                alc * zd.x * inv64 + one_m * xl0[q * 4 + 3]);
        float4 v1 = make_float4(alc * za.y * inv64 + one_m * xl1[q * 4 + 0],
                                alc * zb.y * inv64 + one_m * xl1[q * 4 + 1],
                                alc * zc.y * inv64 + one_m * xl1[q * 4 + 2],
                                alc * zd.y * inv64 + one_m * xl1[q * 4 + 3]);
        ((float4*)dst0)[t * 4 + q] = v0;
        ((float4*)dst1)[t * 4 + q] = v1;
    }
}

// out[b,n,d] = x[b,n,d] + fused[b,d,n]  (tiled transpose-add)
__global__ void k_addout(const float* __restrict__ fused, const float* __restrict__ x,
                         float* __restrict__ out) {
    __shared__ float tile[64][65];
    int d0 = blockIdx.x * 64, n0 = blockIdx.y * 64, b = blockIdx.z;
    int c = threadIdx.x & 63, r4 = threadIdx.x >> 6;
    for (int q = 0; q < 16; ++q) {
        int r = r4 * 16 + q;  // d-row
        tile[r][c] = fused[((size_t)b * D_ + d0 + r) * N_ + n0 + c];
    }
    __syncthreads();
    for (int q = 0; q < 16; ++q) {
        int r = r4 * 16 + q;  // n-row
        size_t o = ((size_t)b * N_ + n0 + r) * D_ + d0 + c;
        out[o] = x[o] + tile[c][r];
    }
}

extern "C" void kernel_launch(void* const* d_in, const int* in_sizes, int n_in,
                              void* d_out, int out_size, void* d_ws, size_t ws_size,
                              hipStream_t stream) {
    const float* x    = (const float*)d_in[0];
    const float* ln_w = (const float*)d_in[1];
    const float* ln_b = (const float*)d_in[2];
    const float* bf_g = (const float*)d_in[3];
    const float* bb_g = (const float*)d_in[4];
    const float* bf_l = (const float*)d_in[5];
    const float* bb_l = (const float*)d_in[6];
    const float* w1g  = (const float*)d_in[7];
    const float* b1g  = (const float*)d_in[8];
    const float* w2g  = (const float*)d_in[9];
    const float* b2g  = (const float*)d_in[10];
    const float* w1l  = (const float*)d_in[11];
    const float* b1l  = (const float*)d_in[12];
    const float* w2l  = (const float*)d_in[13];
    const float* b2l  = (const float*)d_in[14];
    const float* wf1  = (const float*)d_in[15];
    const float* bf1  = (const float*)d_in[16];
    const float* wf2  = (const float*)d_in[17];
    const float* bf2  = (const float*)d_in[18];
    float* out = (float*)d_out;

    char* ws = (char*)d_ws;
    const size_t big = (size_t)B_ * D_ * N_ * sizeof(float);  // ~100.7 MB
    float* XT  = (float*)ws; ws += big;
    float* FU  = (float*)ws; ws += big;   // fused output of spectral
    float* ctx = (float*)ws; ws += (size_t)B_ * D_ * 4;
    float* h1g = (float*)ws; ws += (size_t)B_ * 768 * 4;
    float* h1l = (float*)ws; ws += (size_t)B_ * 768 * 4;
    float* hf  = (float*)ws; ws += (size_t)B_ * 384 * 4;
    float* ag  = (float*)ws; ws += (size_t)B_ * 32784 * 4;
    float* alb = (float*)ws; ws += (size_t)B_ * 80 * 4;
    float* gat = (float*)ws; ws += (size_t)B_ * 8 * 4;
    float2* twg = (float2*)ws; ws += 2048 * sizeof(float2);
    float* hanng = (float*)ws; ws += 4096 * sizeof(float);
    // mu/rstd alias the head of FU: dead before k_spectral writes FU.
    float* mu   = FU;
    float* rstd = FU + 32768;

    k_zero<<<24, 256, 0, stream>>>(ctx, B_ * D_);
    k_tables<<<16, 256, 0, stream>>>(twg, hanng);
    k_stats<<<8192, 256, 0, stream>>>(x, mu, rstd);
    k_lnT<<<dim3(12, 64, 8), 256, 0, stream>>>(x, mu, rstd, ln_w, ln_b, XT, ctx);
    k_mlp1<<<8, 256, 0, stream>>>(ctx, w1g, b1g, w1l, b1l, wf1, bf1, h1g, h1l, hf);
    k_biasinit<<<129, 256, 0, stream>>>(b2g, b2l, ag, alb);
    k_mlp2<<<dim3(129, 8), 256, 0, stream>>>(h1g, h1l, hf, w2g, w2l, wf2, bf2, ag, alb, gat);
    k_spectral<<<B_ * D_ / 2, 256, 0, stream>>>(XT, ag, alb, gat, bf_g, bb_g, bf_l, bb_l,
                                                twg, hanng, FU);
    k_addout<<<dim3(12, 64, 8), 256, 0, stream>>>(FU, x, out);
}

// Round 2
// 681.860 us; speedup vs baseline: 1.0364x; 1.0280x over previous
//
#include <hip/hip_runtime.h>
#include <math.h>

#define B_ 8
#define N_ 4096
#define D_ 768
#define H_ 8
#define HD_ 96
#define FG_ 2049
#define TWO_PI 6.283185307179586476925f
// LDS anti-bank-conflict padding: one extra slot per 32
#define PAD(i) ((i) + ((i) >> 5))

__device__ __forceinline__ float gelu_f(float x) {
    return 0.5f * x * (1.0f + erff(x * 0.7071067811865475f));
}

// One-time init: twiddle W[k] (float2), Hann(4096), ctx zero, ag/al bias init.
__global__ void k_init(const float* __restrict__ b2g, const float* __restrict__ b2l,
                       float2* __restrict__ twg, float* __restrict__ hanng,
                       float* __restrict__ ctx, float* __restrict__ ag,
                       float* __restrict__ al) {
    int i = blockIdx.x * 256 + threadIdx.x;
    if (i < 2048) {
        float s, c;
        sincosf(-TWO_PI * (float)i / 4096.0f, &s, &c);
        twg[i] = make_float2(c, s);
    }
    if (i < 4096) hanng[i] = 0.5f - 0.5f * cosf(TWO_PI * (float)i / 4095.0f);
    if (i < B_ * D_) ctx[i] = 0.f;
    const int CG = H_ * FG_ * 2;  // 32784
    if (i < CG) {
        float v = b2g[i];
        for (int b = 0; b < B_; ++b) ag[(size_t)b * CG + i] = v;
    } else if (i < CG + 80) {
        int cc = i - CG;
        float v = b2l[cc];
        for (int b = 0; b < B_; ++b) al[b * 80 + cc] = v;
    }
}

// Wave-per-row LayerNorm stats: mu, rstd per (b,n) row. 4 waves/block.
__global__ __launch_bounds__(256) void k_stats(const float* __restrict__ x,
                                               float* __restrict__ mu,
                                               float* __restrict__ rstd) {
    int row = blockIdx.x * 4 + (threadIdx.x >> 6);
    int lane = threadIdx.x & 63;
    const float4* xr = (const float4*)(x + (size_t)row * D_);
    float4 a = xr[lane], b = xr[lane + 64], c = xr[lane + 128];
    float s = a.x + a.y + a.z + a.w + b.x + b.y + b.z + b.w + c.x + c.y + c.z + c.w;
    #pragma unroll
    for (int o = 32; o > 0; o >>= 1) s += __shfl_xor(s, o);
    float m = s * (1.0f / 768.0f);
    float v = 0.f, d;
    d = a.x - m; v += d * d; d = a.y - m; v += d * d;
    d = a.z - m; v += d * d; d = a.w - m; v += d * d;
    d = b.x - m; v += d * d; d = b.y - m; v += d * d;
    d = b.z - m; v += d * d; d = b.w - m; v += d * d;
    d = c.x - m; v += d * d; d = c.y - m; v += d * d;
    d = c.z - m; v += d * d; d = c.w - m; v += d * d;
    #pragma unroll
    for (int o = 32; o > 0; o >>= 1) v += __shfl_xor(v, o);
    if (lane == 0) {
        mu[row] = m;
        rstd[row] = rsqrtf(v * (1.0f / 768.0f) + 1e-5f);
    }
}

// Fused: normalize + transposed write [B][D][N] + ctx partial sums (atomics).
__global__ __launch_bounds__(256) void k_lnT(const float* __restrict__ x,
                                             const float* __restrict__ mu,
                                             const float* __restrict__ rstd,
                                             const float* __restrict__ lw,
                                             const float* __restrict__ lb,
                                             float* __restrict__ xt,
                                             float* __restrict__ ctx) {
    __shared__ float tile[64][65];
    __shared__ float csum[4][64];
    int d0 = blockIdx.x * 64, n0 = blockIdx.y * 64, b = blockIdx.z;
    int c = threadIdx.x & 63, r4 = threadIdx.x >> 6;
    float w = lw[d0 + c], bias = lb[d0 + c];
    float partial = 0.f;
    #pragma unroll
    for (int q = 0; q < 16; ++q) {
        int r = r4 * 16 + q;
        int row = b * N_ + n0 + r;
        float v = (x[(size_t)row * D_ + d0 + c] - mu[row]) * rstd[row] * w + bias;
        tile[r][c] = v;
        partial += v;
    }
    csum[r4][c] = partial;
    __syncthreads();
    if (r4 == 0)
        atomicAdd(ctx + b * D_ + d0 + c,
                  (csum[0][c] + csum[1][c] + csum[2][c] + csum[3][c]) * (1.0f / 4096.0f));
    #pragma unroll
    for (int q = 0; q < 16; ++q) {
        int r = r4 * 16 + q;  // d-row
        xt[((size_t)b * D_ + d0 + r) * N_ + n0 + c] = tile[c][r];
    }
}

// h1g = gelu(ctx@w1g+b1g), h1l = gelu(ctx@w1l+b1l), hf = gelu(ctx@wf1+bf1)
__global__ void k_mlp1(const float* __restrict__ ctx,
                       const float* __restrict__ w1g, const float* __restrict__ b1g,
                       const float* __restrict__ w1l, const float* __restrict__ b1l,
                       const float* __restrict__ wf1, const float* __restrict__ bf1,
                       float* __restrict__ h1g, float* __restrict__ h1l, float* __restrict__ hf) {
    __shared__ float cl[B_ * D_];
    for (int i = threadIdx.x; i < B_ * D_; i += 256) cl[i] = ctx[i];
    __syncthreads();
    int c = blockIdx.x * 256 + threadIdx.x;
    if (c >= 1920) return;
    const float *w, *bias; float* out; int ncol, cc;
    if (c < 768)      { w = w1g; bias = b1g; out = h1g; ncol = 768; cc = c; }
    else if (c < 1536){ w = w1l; bias = b1l; out = h1l; ncol = 768; cc = c - 768; }
    else              { w = wf1; bias = bf1; out = hf;  ncol = 384; cc = c - 1536; }
    float acc[B_];
    #pragma unroll
    for (int b = 0; b < B_; ++b) acc[b] = 0.f;
    for (int d = 0; d < 768; ++d) {
        float wv = w[(size_t)d * ncol + cc];
        #pragma unroll
        for (int b = 0; b < B_; ++b) acc[b] += cl[b * 768 + d] * wv;
    }
    float bv = bias[cc];
    for (int b = 0; b < B_; ++b) out[b * ncol + cc] = gelu_f(acc[b] + bv);
}

// split-K (8 chunks of 96): ag += h1g@w2g chunk; al += h1l@w2l chunk; gate full.
__global__ void k_mlp2(const float* __restrict__ h1g, const float* __restrict__ h1l,
                       const float* __restrict__ hf,
                       const float* __restrict__ w2g, const float* __restrict__ w2l,
                       const float* __restrict__ wf2, const float* __restrict__ bf2,
                       float* __restrict__ ag, float* __restrict__ al, float* __restrict__ gate) {
    int kc = blockIdx.y;       // 0..7
    int d0 = kc * 96;
    __shared__ float lg[B_ * 96];
    __shared__ float ll[B_ * 96];
    for (int i = threadIdx.x; i < B_ * 96; i += 256) {
        int bb = i / 96, dd = i % 96;
        lg[i] = h1g[bb * 768 + d0 + dd];
        ll[i] = h1l[bb * 768 + d0 + dd];
    }
    __syncthreads();
    int c = blockIdx.x * 256 + threadIdx.x;
    const int CG = H_ * FG_ * 2;  // 32784
    float acc[B_];
    #pragma unroll
    for (int b = 0; b < B_; ++b) acc[b] = 0.f;
    if (c < CG) {
        for (int d = 0; d < 96; ++d) {
            float wv = w2g[(size_t)(d0 + d) * CG + c];
            #pragma unroll
            for (int b = 0; b < B_; ++b) acc[b] += lg[b * 96 + d] * wv;
        }
        for (int b = 0; b < B_; ++b) atomicAdd(ag + (size_t)b * CG + c, acc[b]);
    } else if (c < CG + 80) {
        int cc = c - CG;
        for (int d = 0; d < 96; ++d) {
            float wv = w2l[(d0 + d) * 80 + cc];
            #pragma unroll
            for (int b = 0; b < B_; ++b) acc[b] += ll[b * 96 + d] * wv;
        }
        for (int b = 0; b < B_; ++b) atomicAdd(al + b * 80 + cc, acc[b]);
    } else if (c < CG + 88 && kc == 0) {
        int cc = c - CG - 80;
        for (int d = 0; d < 384; ++d) {
            float wv = wf2[d * 8 + cc];
            #pragma unroll
            for (int b = 0; b < B_; ++b) acc[b] += hf[b * 384 + d] * wv;
        }
        for (int b = 0; b < B_; ++b)
            gate[b * 8 + cc] = 1.0f / (1.0f + expf(-(acc[b] + bf2[cc])));
    }
}

// One FFT pass: stages 1-4 in registers (per-thread 16-element block,
// constant W16 twiddles), stages 5-12 in LDS (float2, b64 accesses).
__device__ __forceinline__ void fft_pass(float2* z, const float2* tw4,
                                         const float2* __restrict__ twg,
                                         int t, float sign) {
    float2 v[16];
    #pragma unroll
    for (int i = 0; i < 16; ++i) v[i] = z[PAD(t * 16 + i)];
    const float TC[8] = {1.f, 0.92387953251f, 0.70710678119f, 0.38268343236f,
                         0.f, -0.38268343236f, -0.70710678119f, -0.92387953251f};
    const float TS[8] = {0.f, -0.38268343236f, -0.70710678119f, -0.92387953251f,
                         -1.f, -0.92387953251f, -0.70710678119f, -0.38268343236f};
    #pragma unroll
    for (int s = 1; s <= 4; ++s) {
        int half = 1 << (s - 1);
        #pragma unroll
        for (int u = 0; u < 8; ++u) {
            int lg = u >> (s - 1), pos = u & (half - 1);
            int i1 = (lg << s) + pos, i2 = i1 + half;
            int m = pos << (4 - s);
            float wr = TC[m], wi = sign * TS[m];
            float2 a = v[i1], bb = v[i2];
            float tr = bb.x * wr - bb.y * wi;
            float ti = bb.x * wi + bb.y * wr;
            v[i1] = make_float2(a.x + tr, a.y + ti);
            v[i2] = make_float2(a.x - tr, a.y - ti);
        }
    }
    #pragma unroll
    for (int i = 0; i < 16; ++i) z[PAD(t * 16 + i)] = v[i];
    __syncthreads();
    // stages 5..10: twiddles from LDS tw4 (W^(4m))
    for (int s = 5; s <= 10; ++s) {
        int half = 1 << (s - 1);
        int sh = 12 - s;
        #pragma unroll
        for (int u = 0; u < 8; ++u) {
            int j = t + (u << 8);
            int grp = j >> (s - 1);
            int pos = j & (half - 1);
            int i1 = (grp << s) + pos;
            int p1 = PAD(i1), p2 = PAD(i1 + half);
            float2 w = tw4[PAD(pos << (sh - 2))];
            float wi = sign * w.y;
            float2 a = z[p1], bb = z[p2];
            float tr = bb.x * w.x - bb.y * wi;
            float ti = bb.x * wi + bb.y * w.x;
            z[p1] = make_float2(a.x + tr, a.y + ti);
            z[p2] = make_float2(a.x - tr, a.y - ti);
        }
        __syncthreads();
    }
    // stages 11..12: twiddles straight from global (L1-resident 16KB table)
    for (int s = 11; s <= 12; ++s) {
        int half = 1 << (s - 1);
        int sh = 12 - s;
        #pragma unroll
        for (int u = 0; u < 8; ++u) {
            int j = t + (u << 8);
            int grp = j >> (s - 1);
            int pos = j & (half - 1);
            int i1 = (grp << s) + pos;
            int p1 = PAD(i1), p2 = PAD(i1 + half);
            float2 w = twg[pos << sh];
            float wi = sign * w.y;
            float2 a = z[p1], bb = z[p2];
            float tr = bb.x * w.x - bb.y * wi;
            float ti = bb.x * wi + bb.y * w.x;
            z[p1] = make_float2(a.x + tr, a.y + ti);
            z[p2] = make_float2(a.x - tr, a.y - ti);
        }
        __syncthreads();
    }
}

// One block per PAIR of lines (2m, 2m+1): packed complex FFT does both.
__global__ __launch_bounds__(256) void k_spectral(
        const float* __restrict__ xt,    // [B][D][N]
        const float* __restrict__ ag,    // [B][32784]
        const float* __restrict__ al,    // [B][80]
        const float* __restrict__ gate,  // [B][8]
        const float* __restrict__ bf_g, const float* __restrict__ bb_g,
        const float* __restrict__ bf_l, const float* __restrict__ bb_l,
        const float2* __restrict__ twg, const float* __restrict__ hanng,
        float* __restrict__ fused)       // [B][D][N]
{
    __shared__ float2 z[4224];
    __shared__ float2 tw4[528];   // W^(4m), m<512, padded
    int line0 = blockIdx.x * 2;   // b*768 + d0, d0 even
    int d0 = line0 % 768, b = line0 / 768;
    int h = d0 / HD_;             // both lines share h (HD=96 even)
    int t = threadIdx.x;

    for (int m = t; m < 512; m += 256) tw4[PAD(m)] = twg[4 * m];

    // load both raw lines (16 contiguous n per thread each)
    const float* src0 = xt + (size_t)line0 * N_;
    const float* src1 = src0 + N_;
    float raw0[16], raw1[16];
    #pragma unroll
    for (int q = 0; q < 4; ++q) {
        float4 v0 = ((const float4*)src0)[t * 4 + q];
        float4 v1 = ((const float4*)src1)[t * 4 + q];
        raw0[q * 4 + 0] = v0.x; raw0[q * 4 + 1] = v0.y;
        raw0[q * 4 + 2] = v0.z; raw0[q * 4 + 3] = v0.w;
        raw1[q * 4 + 0] = v1.x; raw1[q * 4 + 1] = v1.y;
        raw1[q * 4 + 2] = v1.z; raw1[q * 4 + 3] = v1.w;
    }
    // deposit packed complex z = x0 + i*x1, Hann-windowed, bit-reversed
    #pragma unroll
    for (int q = 0; q < 4; ++q) {
        float4 hw = ((const float4*)hanng)[t * 4 + q];
        int nb = t * 16 + q * 4;
        int r0 = PAD((int)(__brev((unsigned)(nb + 0)) >> 20));
        int r1 = PAD((int)(__brev((unsigned)(nb + 1)) >> 20));
        int r2 = PAD((int)(__brev((unsigned)(nb + 2)) >> 20));
        int r3 = PAD((int)(__brev((unsigned)(nb + 3)) >> 20));
        z[r0] = make_float2(raw0[q * 4 + 0] * hw.x, raw1[q * 4 + 0] * hw.x);
        z[r1] = make_float2(raw0[q * 4 + 1] * hw.y, raw1[q * 4 + 1] * hw.y);
        z[r2] = make_float2(raw0[q * 4 + 2] * hw.z, raw1[q * 4 + 2] * hw.z);
        z[r3] = make_float2(raw0[q * 4 + 3] * hw.w, raw1[q * 4 + 3] * hw.w);
    }

    // ---- local branch in registers (2 windows of 8 per thread, both lines) ----
    float alc = gate[b * 8 + h];
    const float* alb = al + b * 80;
    float effl_f[5], effl_b[5];
    #pragma unroll
    for (int f = 0; f < 5; ++f) {
        int idx = h * 5 + f;
        effl_f[f] = bf_l[idx] * (1.0f + alb[idx * 2]);
        effl_b[f] = bb_l[idx] + alb[idx * 2 + 1];
    }
    const float s8 = 0.3535533905932738f;  // 1/sqrt(8)
    const float c7 = 0.7071067811865476f;
    const float cosT[8] = {1.f, c7, 0.f, -c7, -1.f, -c7, 0.f, c7};
    const float sinT[8] = {0.f, c7, 1.f, c7, 0.f, -c7, -1.f, -c7};
    const float hl[8] = {0.f, 0.18825510f, 0.61126047f, 0.95048444f,
                         0.95048444f, 0.61126047f, 0.18825510f, 0.f};
    float xl0[16], xl1[16];
    #pragma unroll
    for (int ln = 0; ln < 2; ++ln) {
        float* rawp = ln ? raw1 : raw0;
        float* xlp  = ln ? xl1 : xl0;
        #pragma unroll
        for (int w2 = 0; w2 < 2; ++w2) {
            float xw[8];
            #pragma unroll
            for (int j = 0; j < 8; ++j) xw[j] = rawp[w2 * 8 + j] * hl[j];
            float Yr[5], Yi[5];
            #pragma unroll
            for (int f = 0; f < 5; ++f) {
                float fr = 0.f, fi = 0.f;
                #pragma unroll
                for (int j = 0; j < 8; ++j) {
                    int k8 = (f * j) & 7;
                    fr += xw[j] * cosT[k8];
                    fi -= xw[j] * sinT[k8];
                }
                fr *= s8; fi *= s8;
                float zr = fr * effl_f[f] + effl_b[f];
                float zi = fi * effl_f[f];
                float mag = sqrtf(zr * zr + zi * zi);
                float g = gelu_f(mag) / (mag + 1e-6f);
                Yr[f] = zr * g; Yi[f] = zi * g;
            }
            #pragma unroll
            for (int j = 0; j < 8; ++j) {
                float acc = Yr[0] + Yr[4] * ((j & 1) ? -1.f : 1.f);
                #pragma unroll
                for (int f = 1; f < 4; ++f) {
                    int k8 = (f * j) & 7;
                    acc += 2.f * (Yr[f] * cosT[k8] - Yi[f] * sinT[k8]);
                }
                xlp[w2 * 8 + j] = acc * s8;
            }
        }
    }

    __syncthreads();
    // forward FFT: Z = FFT(x0 + i*x1), natural order out
    fft_pass(z, tw4, twg, t, 1.0f);

    // Hermitian split + modulate + cgelu + re-pack (in place; thread owns {k, 4096-k})
    const float inv64 = 1.0f / 64.0f;
    const float* agb = ag + (size_t)b * 32784;
    for (int k = t; k < 2048; k += 256) {
        int km = (4096 - k) & 4095;
        int pk = PAD(k), pm = PAD(km);
        float2 Z = z[pk], Z2 = z[pm];
        float X0r = 0.5f * (Z.x + Z2.x), X0i = 0.5f * (Z.y - Z2.y);
        float X1r = 0.5f * (Z.y + Z2.y), X1i = -0.5f * (Z.x - Z2.x);
        int idx = h * FG_ + k;
        float efff = bf_g[idx] * (1.0f + agb[idx * 2]);
        float effb = bb_g[idx] + agb[idx * 2 + 1];
        float z0r = X0r * inv64 * efff + effb, z0i = X0i * inv64 * efff;
        float m0 = sqrtf(z0r * z0r + z0i * z0i);
        float g0 = gelu_f(m0) / (m0 + 1e-6f);
        float Y0r = z0r * g0, Y0i = z0i * g0;
        float z1r = X1r * inv64 * efff + effb, z1i = X1i * inv64 * efff;
        float m1 = sqrtf(z1r * z1r + z1i * z1i);
        float g1 = gelu_f(m1) / (m1 + 1e-6f);
        float Y1r = z1r * g1, Y1i = z1i * g1;
        z[pk] = make_float2(Y0r - Y1i, Y0i + Y1r);
        if (k) z[pm] = make_float2(Y0r + Y1i, Y1r - Y0i);
    }
    if (t == 0) {  // Nyquist bin k=2048 (self-mirror; X0,X1 real)
        int pk = PAD(2048);
        float2 Z = z[pk];
        int idx = h * FG_ + 2048;
        float efff = bf_g[idx] * (1.0f + agb[idx * 2]);
        float effb = bb_g[idx] + agb[idx * 2 + 1];
        float z0r = Z.x * inv64 * efff + effb;
        float m0 = fabsf(z0r);
        float Y0r = z0r * (gelu_f(m0) / (m0 + 1e-6f));
        float z1r = Z.y * inv64 * efff + effb;
        float m1 = fabsf(z1r);
        float Y1r = z1r * (gelu_f(m1) / (m1 + 1e-6f));
        z[pk] = make_float2(Y0r, Y1r);
    }
    __syncthreads();
    // bit-reverse permutation (padded)
    for (int n = t; n < 4096; n += 256) {
        int r = (int)(__brev((unsigned)n) >> 20);
        if (r > n) {
            int pn = PAD(n), pr = PAD(r);
            float2 a = z[pn]; z[pn] = z[pr]; z[pr] = a;
        }
    }
    __syncthreads();
    // inverse FFT: w = N*IDFT(P); y0 = Re(w)/64, y1 = Im(w)/64
    fft_pass(z, tw4, twg, t, -1.0f);

    // fuse and store both lines
    float* dst0 = fused + (size_t)line0 * N_;
    float* dst1 = dst0 + N_;
    float one_m = 1.0f - alc;
    #pragma unroll
    for (int q = 0; q < 4; ++q) {
        int base = t * 16 + q * 4;
        float2 za = z[PAD(base + 0)], zb = z[PAD(base + 1)];
        float2 zc = z[PAD(base + 2)], zd = z[PAD(base + 3)];
        float4 v0 = make_float4(alc * za.x * inv64 + one_m * xl0[q * 4 + 0],
                                alc * zb.x * inv64 + one_m * xl0[q * 4 + 1],
                                alc * zc.x * inv64 + one_m * xl0[q * 4 + 2],
                                alc * zd.x * inv64 + one_m * xl0[q * 4 + 3]);
        float4 v1 = make_float4(alc * za.y * inv64 + one_m * xl1[q * 4 + 0],
                                alc * zb.y * inv64 + one_m * xl1[q * 4 + 1],
                                alc * zc.y * inv64 + one_m * xl1[q * 4 + 2],
                                alc * zd.y * inv64 + one_m * xl1[q * 4 + 3]);
        ((float4*)dst0)[t * 4 + q] = v0;
        ((float4*)dst1)[t * 4 + q] = v1;
    }
}

// out[b,n,d] = x[b,n,d] + fused[b,d,n]  (tiled transpose-add)
__global__ void k_addout(const float* __restrict__ fused, const float* __restrict__ x,
                         float* __restrict__ out) {
    __shared__ float tile[64][65];
    int d0 = blockIdx.x * 64, n0 = blockIdx.y * 64, b = blockIdx.z;
    int c = threadIdx.x & 63, r4 = threadIdx.x >> 6;
    for (int q = 0; q < 16; ++q) {
        int r = r4 * 16 + q;  // d-row
        tile[r][c] = fused[((size_t)b * D_ + d0 + r) * N_ + n0 + c];
    }
    __syncthreads();
    for (int q = 0; q < 16; ++q) {
        int r = r4 * 16 + q;  // n-row
        size_t o = ((size_t)b * N_ + n0 + r) * D_ + d0 + c;
        out[o] = x[o] + tile[c][r];
    }
}

extern "C" void kernel_launch(void* const* d_in, const int* in_sizes, int n_in,
                              void* d_out, int out_size, void* d_ws, size_t ws_size,
                              hipStream_t stream) {
    const float* x    = (const float*)d_in[0];
    const float* ln_w = (const float*)d_in[1];
    const float* ln_b = (const float*)d_in[2];
    const float* bf_g = (const float*)d_in[3];
    const float* bb_g = (const float*)d_in[4];
    const float* bf_l = (const float*)d_in[5];
    const float* bb_l = (const float*)d_in[6];
    const float* w1g  = (const float*)d_in[7];
    const float* b1g  = (const float*)d_in[8];
    const float* w2g  = (const float*)d_in[9];
    const float* b2g  = (const float*)d_in[10];
    const float* w1l  = (const float*)d_in[11];
    const float* b1l  = (const float*)d_in[12];
    const float* w2l  = (const float*)d_in[13];
    const float* b2l  = (const float*)d_in[14];
    const float* wf1  = (const float*)d_in[15];
    const float* bf1  = (const float*)d_in[16];
    const float* wf2  = (const float*)d_in[17];
    const float* bf2  = (const float*)d_in[18];
    float* out = (float*)d_out;

    char* ws = (char*)d_ws;
    const size_t big = (size_t)B_ * D_ * N_ * sizeof(float);  // ~100.7 MB
    float* XT  = (float*)ws; ws += big;
    float* FU  = (float*)ws; ws += big;   // fused output of spectral
    float* ctx = (float*)ws; ws += (size_t)B_ * D_ * 4;
    float* h1g = (float*)ws; ws += (size_t)B_ * 768 * 4;
    float* h1l = (float*)ws; ws += (size_t)B_ * 768 * 4;
    float* hf  = (float*)ws; ws += (size_t)B_ * 384 * 4;
    float* ag  = (float*)ws; ws += (size_t)B_ * 32784 * 4;
    float* alb = (float*)ws; ws += (size_t)B_ * 80 * 4;
    float* gat = (float*)ws; ws += (size_t)B_ * 8 * 4;
    float2* twg = (float2*)ws; ws += 2048 * sizeof(float2);
    float* hanng = (float*)ws; ws += 4096 * sizeof(float);
    // mu/rstd alias the head of FU: dead before k_spectral writes FU.
    float* mu   = FU;
    float* rstd = FU + 32768;

    k_init<<<129, 256, 0, stream>>>(b2g, b2l, twg, hanng, ctx, ag, alb);
    k_stats<<<8192, 256, 0, stream>>>(x, mu, rstd);
    k_lnT<<<dim3(12, 64, 8), 256, 0, stream>>>(x, mu, rstd, ln_w, ln_b, XT, ctx);
    k_mlp1<<<8, 256, 0, stream>>>(ctx, w1g, b1g, w1l, b1l, wf1, bf1, h1g, h1l, hf);
    k_mlp2<<<dim3(129, 8), 256, 0, stream>>>(h1g, h1l, hf, w2g, w2l, wf2, bf2, ag, alb, gat);
    k_spectral<<<B_ * D_ / 2, 256, 0, stream>>>(XT, ag, alb, gat, bf_g, bb_g, bf_l, bb_l,
                                                twg, hanng, FU);
    k_addout<<<dim3(12, 64, 8), 256, 0, stream>>>(FU, x, out);
}

// Round 3
// 610.702 us; speedup vs baseline: 1.1571x; 1.1165x over previous
//
#include <hip/hip_runtime.h>
#include <math.h>

#define B_ 8
#define N_ 4096
#define D_ 768
#define H_ 8
#define HD_ 96
#define FG_ 2049
#define TWO_PI 6.283185307179586476925f
// LDS anti-bank-conflict padding: one extra slot per 32
#define PAD(i) ((i) + ((i) >> 5))

// Abramowitz-Stegun 7.1.26: |err| <= 1.5e-7, much cheaper than libm erff.
__device__ __forceinline__ float erf_fast(float x) {
    float ax = fabsf(x);
    float t = __builtin_amdgcn_rcpf(fmaf(0.3275911f, ax, 1.0f));
    float p = fmaf(fmaf(fmaf(fmaf(1.061405429f, t, -1.453152027f), t, 1.421413741f),
                        t, -0.284496736f), t, 0.254829592f) * t;
    float r = 1.0f - p * __expf(-ax * ax);
    return copysignf(r, x);
}

__device__ __forceinline__ float gelu_f(float x) {
    return 0.5f * x * (1.0f + erf_fast(x * 0.7071067811865475f));
}

// base-4 digit reversal of a 12-bit index (involution)
__device__ __forceinline__ int rev4_12(int x) {
    int r = (int)(__brev((unsigned)x) >> 20);
    return ((r & 0x555) << 1) | ((r >> 1) & 0x555);
}

// One-time init: twiddle W[k] (float2), Hann(4096), ctx zero, ag/al bias init.
__global__ void k_init(const float* __restrict__ b2g, const float* __restrict__ b2l,
                       float2* __restrict__ twg, float* __restrict__ hanng,
                       float* __restrict__ ctx, float* __restrict__ ag,
                       float* __restrict__ al) {
    int i = blockIdx.x * 256 + threadIdx.x;
    if (i < 2048) {
        float s, c;
        sincosf(-TWO_PI * (float)i / 4096.0f, &s, &c);
        twg[i] = make_float2(c, s);
    }
    if (i < 4096) hanng[i] = 0.5f - 0.5f * cosf(TWO_PI * (float)i / 4095.0f);
    if (i < B_ * D_) ctx[i] = 0.f;
    const int CG = H_ * FG_ * 2;  // 32784
    if (i < CG) {
        float v = b2g[i];
        for (int b = 0; b < B_; ++b) ag[(size_t)b * CG + i] = v;
    } else if (i < CG + 80) {
        int cc = i - CG;
        float v = b2l[cc];
        for (int b = 0; b < B_; ++b) al[b * 80 + cc] = v;
    }
}

// Wave-per-row LayerNorm stats: mu, rstd per (b,n) row. 4 waves/block.
__global__ __launch_bounds__(256) void k_stats(const float* __restrict__ x,
                                               float* __restrict__ mu,
                                               float* __restrict__ rstd) {
    int row = blockIdx.x * 4 + (threadIdx.x >> 6);
    int lane = threadIdx.x & 63;
    const float4* xr = (const float4*)(x + (size_t)row * D_);
    float4 a = xr[lane], b = xr[lane + 64], c = xr[lane + 128];
    float s = a.x + a.y + a.z + a.w + b.x + b.y + b.z + b.w + c.x + c.y + c.z + c.w;
    #pragma unroll
    for (int o = 32; o > 0; o >>= 1) s += __shfl_xor(s, o);
    float m = s * (1.0f / 768.0f);
    float v = 0.f, d;
    d = a.x - m; v += d * d; d = a.y - m; v += d * d;
    d = a.z - m; v += d * d; d = a.w - m; v += d * d;
    d = b.x - m; v += d * d; d = b.y - m; v += d * d;
    d = b.z - m; v += d * d; d = b.w - m; v += d * d;
    d = c.x - m; v += d * d; d = c.y - m; v += d * d;
    d = c.z - m; v += d * d; d = c.w - m; v += d * d;
    #pragma unroll
    for (int o = 32; o > 0; o >>= 1) v += __shfl_xor(v, o);
    if (lane == 0) {
        mu[row] = m;
        rstd[row] = rsqrtf(v * (1.0f / 768.0f) + 1e-5f);
    }
}

// Fused: normalize + transposed write [B][D][N] + ctx partial sums (atomics).
__global__ __launch_bounds__(256) void k_lnT(const float* __restrict__ x,
                                             const float* __restrict__ mu,
                                             const float* __restrict__ rstd,
                                             const float* __restrict__ lw,
                                             const float* __restrict__ lb,
                                             float* __restrict__ xt,
                                             float* __restrict__ ctx) {
    __shared__ float tile[64][65];
    __shared__ float csum[4][64];
    int d0 = blockIdx.x * 64, n0 = blockIdx.y * 64, b = blockIdx.z;
    int c = threadIdx.x & 63, r4 = threadIdx.x >> 6;
    float w = lw[d0 + c], bias = lb[d0 + c];
    float partial = 0.f;
    #pragma unroll
    for (int q = 0; q < 16; ++q) {
        int r = r4 * 16 + q;
        int row = b * N_ + n0 + r;
        float v = (x[(size_t)row * D_ + d0 + c] - mu[row]) * rstd[row] * w + bias;
        tile[r][c] = v;
        partial += v;
    }
    csum[r4][c] = partial;
    __syncthreads();
    if (r4 == 0)
        atomicAdd(ctx + b * D_ + d0 + c,
                  (csum[0][c] + csum[1][c] + csum[2][c] + csum[3][c]) * (1.0f / 4096.0f));
    #pragma unroll
    for (int q = 0; q < 16; ++q) {
        int r = r4 * 16 + q;  // d-row
        xt[((size_t)b * D_ + d0 + r) * N_ + n0 + c] = tile[c][r];
    }
}

// h1g = gelu(ctx@w1g+b1g), h1l = gelu(ctx@w1l+b1l), hf = gelu(ctx@wf1+bf1)
__global__ void k_mlp1(const float* __restrict__ ctx,
                       const float* __restrict__ w1g, const float* __restrict__ b1g,
                       const float* __restrict__ w1l, const float* __restrict__ b1l,
                       const float* __restrict__ wf1, const float* __restrict__ bf1,
                       float* __restrict__ h1g, float* __restrict__ h1l, float* __restrict__ hf) {
    __shared__ float cl[B_ * D_];
    for (int i = threadIdx.x; i < B_ * D_; i += 256) cl[i] = ctx[i];
    __syncthreads();
    int c = blockIdx.x * 256 + threadIdx.x;
    if (c >= 1920) return;
    const float *w, *bias; float* out; int ncol, cc;
    if (c < 768)      { w = w1g; bias = b1g; out = h1g; ncol = 768; cc = c; }
    else if (c < 1536){ w = w1l; bias = b1l; out = h1l; ncol = 768; cc = c - 768; }
    else              { w = wf1; bias = bf1; out = hf;  ncol = 384; cc = c - 1536; }
    float acc[B_];
    #pragma unroll
    for (int b = 0; b < B_; ++b) acc[b] = 0.f;
    for (int d = 0; d < 768; ++d) {
        float wv = w[(size_t)d * ncol + cc];
        #pragma unroll
        for (int b = 0; b < B_; ++b) acc[b] += cl[b * 768 + d] * wv;
    }
    float bv = bias[cc];
    for (int b = 0; b < B_; ++b) out[b * ncol + cc] = gelu_f(acc[b] + bv);
}

// split-K (8 chunks of 96): ag += h1g@w2g chunk; al += h1l@w2l chunk; gate full.
__global__ void k_mlp2(const float* __restrict__ h1g, const float* __restrict__ h1l,
                       const float* __restrict__ hf,
                       const float* __restrict__ w2g, const float* __restrict__ w2l,
                       const float* __restrict__ wf2, const float* __restrict__ bf2,
                       float* __restrict__ ag, float* __restrict__ al, float* __restrict__ gate) {
    int kc = blockIdx.y;       // 0..7
    int d0 = kc * 96;
    __shared__ float lg[B_ * 96];
    __shared__ float ll[B_ * 96];
    for (int i = threadIdx.x; i < B_ * 96; i += 256) {
        int bb = i / 96, dd = i % 96;
        lg[i] = h1g[bb * 768 + d0 + dd];
        ll[i] = h1l[bb * 768 + d0 + dd];
    }
    __syncthreads();
    int c = blockIdx.x * 256 + threadIdx.x;
    const int CG = H_ * FG_ * 2;  // 32784
    float acc[B_];
    #pragma unroll
    for (int b = 0; b < B_; ++b) acc[b] = 0.f;
    if (c < CG) {
        for (int d = 0; d < 96; ++d) {
            float wv = w2g[(size_t)(d0 + d) * CG + c];
            #pragma unroll
            for (int b = 0; b < B_; ++b) acc[b] += lg[b * 96 + d] * wv;
        }
        for (int b = 0; b < B_; ++b) atomicAdd(ag + (size_t)b * CG + c, acc[b]);
    } else if (c < CG + 80) {
        int cc = c - CG;
        for (int d = 0; d < 96; ++d) {
            float wv = w2l[(d0 + d) * 80 + cc];
            #pragma unroll
            for (int b = 0; b < B_; ++b) acc[b] += ll[b * 96 + d] * wv;
        }
        for (int b = 0; b < B_; ++b) atomicAdd(al + b * 80 + cc, acc[b]);
    } else if (c < CG + 88 && kc == 0) {
        int cc = c - CG - 80;
        for (int d = 0; d < 384; ++d) {
            float wv = wf2[d * 8 + cc];
            #pragma unroll
            for (int b = 0; b < B_; ++b) acc[b] += hf[b * 384 + d] * wv;
        }
        for (int b = 0; b < B_; ++b)
            gate[b * 8 + cc] = 1.0f / (1.0f + expf(-(acc[b] + bf2[cc])));
    }
}

// ---- radix-4 DIF stage (forward). 1024 butterflies, 4 per thread. ----
// Twiddles: w1 = W^(pos*f) from global (L1), w2 = w1^2, w3 = w1*w2.
template<int LQ>
__device__ __forceinline__ void dif_stage(float2* z, const float2* __restrict__ twg, int t) {
    const int Q = 1 << LQ;
    #pragma unroll
    for (int u = 0; u < 4; ++u) {
        int j = t + (u << 8);
        int pos = j & (Q - 1);
        int i0 = ((j >> LQ) << (LQ + 2)) + pos;
        int p0 = PAD(i0), p1 = PAD(i0 + Q), p2 = PAD(i0 + 2 * Q), p3 = PAD(i0 + 3 * Q);
        float2 a = z[p0], bq = z[p1], c = z[p2], d = z[p3];
        float t0x = a.x + c.x,  t0y = a.y + c.y;
        float t1x = a.x - c.x,  t1y = a.y - c.y;
        float t2x = bq.x + d.x, t2y = bq.y + d.y;
        float t3x = bq.x - d.x, t3y = bq.y - d.y;
        float2 w1 = twg[pos << (10 - LQ)];
        float2 w2 = make_float2(w1.x * w1.x - w1.y * w1.y, 2.f * w1.x * w1.y);
        float2 w3 = make_float2(w1.x * w2.x - w1.y * w2.y, w1.x * w2.y + w1.y * w2.x);
        z[p0] = make_float2(t0x + t2x, t0y + t2y);
        float y1x = t1x + t3y, y1y = t1y - t3x;   // t1 - i*t3
        z[p1] = make_float2(y1x * w1.x - y1y * w1.y, y1x * w1.y + y1y * w1.x);
        float y2x = t0x - t2x, y2y = t0y - t2y;
        z[p2] = make_float2(y2x * w2.x - y2y * w2.y, y2x * w2.y + y2y * w2.x);
        float y3x = t1x - t3y, y3y = t1y + t3x;   // t1 + i*t3
        z[p3] = make_float2(y3x * w3.x - y3y * w3.y, y3x * w3.y + y3y * w3.x);
    }
}

// ---- radix-4 DIT stage (inverse, conj twiddles applied to inputs). ----
template<int LQ>
__device__ __forceinline__ void dit_stage(float2* z, const float2* __restrict__ twg, int t) {
    const int Q = 1 << LQ;
    #pragma unroll
    for (int u = 0; u < 4; ++u) {
        int j = t + (u << 8);
        int pos = j & (Q - 1);
        int i0 = ((j >> LQ) << (LQ + 2)) + pos;
        int p0 = PAD(i0), p1 = PAD(i0 + Q), p2 = PAD(i0 + 2 * Q), p3 = PAD(i0 + 3 * Q);
        float2 a = z[p0], bq = z[p1], c = z[p2], d = z[p3];
        float2 w1 = twg[pos << (10 - LQ)];
        w1.y = -w1.y;
        float2 w2 = make_float2(w1.x * w1.x - w1.y * w1.y, 2.f * w1.x * w1.y);
        float2 w3 = make_float2(w1.x * w2.x - w1.y * w2.y, w1.x * w2.y + w1.y * w2.x);
        float2 bh = make_float2(bq.x * w1.x - bq.y * w1.y, bq.x * w1.y + bq.y * w1.x);
        float2 ch = make_float2(c.x * w2.x - c.y * w2.y, c.x * w2.y + c.y * w2.x);
        float2 dh = make_float2(d.x * w3.x - d.y * w3.y, d.x * w3.y + d.y * w3.x);
        float t0x = a.x + ch.x,  t0y = a.y + ch.y;
        float t1x = a.x - ch.x,  t1y = a.y - ch.y;
        float t2x = bh.x + dh.x, t2y = bh.y + dh.y;
        float t3x = bh.x - dh.x, t3y = bh.y - dh.y;
        z[p0] = make_float2(t0x + t2x, t0y + t2y);
        z[p1] = make_float2(t1x - t3y, t1y + t3x);   // t1 + i*t3
        z[p2] = make_float2(t0x - t2x, t0y - t2y);
        z[p3] = make_float2(t1x + t3y, t1y - t3x);   // t1 - i*t3
    }
}

#define W16C_INIT {1.f, 0.9238795325f, 0.7071067812f, 0.3826834324f, 0.f, \
                   -0.3826834324f, -0.7071067812f, -0.9238795325f, -1.f, -0.9238795325f}
#define W16S_INIT {0.f, -0.3826834324f, -0.7071067812f, -0.9238795325f, -1.f, \
                   -0.9238795325f, -0.7071067812f, -0.3826834324f, 0.f, 0.3826834324f}

// forward 16-point (two radix-4 stages, constant W16 twiddles), in registers
__device__ __forceinline__ void fwd16(float2* v) {
    const float WC[10] = W16C_INIT;
    const float WS[10] = W16S_INIT;
    #pragma unroll
    for (int n0 = 0; n0 < 4; ++n0) {
        float2 a = v[n0], b = v[n0 + 4], c = v[n0 + 8], d = v[n0 + 12];
        float t0x = a.x + c.x, t0y = a.y + c.y, t1x = a.x - c.x, t1y = a.y - c.y;
        float t2x = b.x + d.x, t2y = b.y + d.y, t3x = b.x - d.x, t3y = b.y - d.y;
        v[n0] = make_float2(t0x + t2x, t0y + t2y);
        float y1x = t1x + t3y, y1y = t1y - t3x;
        float y2x = t0x - t2x, y2y = t0y - t2y;
        float y3x = t1x - t3y, y3y = t1y + t3x;
        v[n0 + 4]  = make_float2(y1x * WC[n0] - y1y * WS[n0], y1x * WS[n0] + y1y * WC[n0]);
        v[n0 + 8]  = make_float2(y2x * WC[2*n0] - y2y * WS[2*n0], y2x * WS[2*n0] + y2y * WC[2*n0]);
        v[n0 + 12] = make_float2(y3x * WC[3*n0] - y3y * WS[3*n0], y3x * WS[3*n0] + y3y * WC[3*n0]);
    }
    #pragma unroll
    for (int g = 0; g < 4; ++g) {
        float2 a = v[4*g], b = v[4*g+1], c = v[4*g+2], d = v[4*g+3];
        float t0x = a.x + c.x, t0y = a.y + c.y, t1x = a.x - c.x, t1y = a.y - c.y;
        float t2x = b.x + d.x, t2y = b.y + d.y, t3x = b.x - d.x, t3y = b.y - d.y;
        v[4*g]   = make_float2(t0x + t2x, t0y + t2y);
        v[4*g+1] = make_float2(t1x + t3y, t1y - t3x);
        v[4*g+2] = make_float2(t0x - t2x, t0y - t2y);
        v[4*g+3] = make_float2(t1x - t3y, t1y + t3x);
    }
}

// inverse 16-point (mirror of fwd16, conj twiddles on inputs)
__device__ __forceinline__ void inv16(float2* v) {
    const float WC[10] = W16C_INIT;
    const float WS[10] = W16S_INIT;
    #pragma unroll
    for (int g = 0; g < 4; ++g) {
        float2 a = v[4*g], b = v[4*g+1], c = v[4*g+2], d = v[4*g+3];
        float t0x = a.x + c.x, t0y = a.y + c.y, t1x = a.x - c.x, t1y = a.y - c.y;
        float t2x = b.x + d.x, t2y = b.y + d.y, t3x = b.x - d.x, t3y = b.y - d.y;
        v[4*g]   = make_float2(t0x + t2x, t0y + t2y);
        v[4*g+1] = make_float2(t1x - t3y, t1y + t3x);
        v[4*g+2] = make_float2(t0x - t2x, t0y - t2y);
        v[4*g+3] = make_float2(t1x + t3y, t1y - t3x);
    }
    #pragma unroll
    for (int n0 = 0; n0 < 4; ++n0) {
        float2 a = v[n0];
        float2 b0 = v[n0 + 4], c0 = v[n0 + 8], dd = v[n0 + 12];
        // multiply by conj(W16^m): (x,y)*(wc,-ws) = (x*wc + y*ws, y*wc - x*ws)
        float2 b = make_float2(b0.x * WC[n0] + b0.y * WS[n0], b0.y * WC[n0] - b0.x * WS[n0]);
        float2 c = make_float2(c0.x * WC[2*n0] + c0.y * WS[2*n0], c0.y * WC[2*n0] - c0.x * WS[2*n0]);
        float2 d = make_float2(dd.x * WC[3*n0] + dd.y * WS[3*n0], dd.y * WC[3*n0] - dd.x * WS[3*n0]);
        float t0x = a.x + c.x, t0y = a.y + c.y, t1x = a.x - c.x, t1y = a.y - c.y;
        float t2x = b.x + d.x, t2y = b.y + d.y, t3x = b.x - d.x, t3y = b.y - d.y;
        v[n0]      = make_float2(t0x + t2x, t0y + t2y);
        v[n0 + 4]  = make_float2(t1x - t3y, t1y + t3x);
        v[n0 + 8]  = make_float2(t0x - t2x, t0y - t2y);
        v[n0 + 12] = make_float2(t1x + t3y, t1y - t3x);
    }
}

// One block per PAIR of lines (2m, 2m+1): packed complex FFT does both.
// Forward: radix-4 DIF (natural in, digit-reversed out). Inverse: radix-4 DIT.
__global__ __launch_bounds__(256) void k_spectral(
        const float* __restrict__ xt,    // [B][D][N]
        const float* __restrict__ ag,    // [B][32784]
        const float* __restrict__ al,    // [B][80]
        const float* __restrict__ gate,  // [B][8]
        const float* __restrict__ bf_g, const float* __restrict__ bb_g,
        const float* __restrict__ bf_l, const float* __restrict__ bb_l,
        const float2* __restrict__ twg, const float* __restrict__ hanng,
        float* __restrict__ fused)       // [B][D][N]
{
    __shared__ float2 z[4224];
    int line0 = blockIdx.x * 2;   // b*768 + d0, d0 even
    int d0 = line0 % 768, b = line0 / 768;
    int h = d0 / HD_;             // both lines share h (HD=96 even)
    int t = threadIdx.x;

    // load both raw lines (16 contiguous n per thread each)
    const float* src0 = xt + (size_t)line0 * N_;
    const float* src1 = src0 + N_;
    float raw0[16], raw1[16];
    #pragma unroll
    for (int q = 0; q < 4; ++q) {
        float4 v0 = ((const float4*)src0)[t * 4 + q];
        float4 v1 = ((const float4*)src1)[t * 4 + q];
        raw0[q * 4 + 0] = v0.x; raw0[q * 4 + 1] = v0.y;
        raw0[q * 4 + 2] = v0.z; raw0[q * 4 + 3] = v0.w;
        raw1[q * 4 + 0] = v1.x; raw1[q * 4 + 1] = v1.y;
        raw1[q * 4 + 2] = v1.z; raw1[q * 4 + 3] = v1.w;
    }
    // deposit packed complex z = x0 + i*x1, Hann-windowed, NATURAL order (DIF)
    #pragma unroll
    for (int q = 0; q < 4; ++q) {
        float4 hw = ((const float4*)hanng)[t * 4 + q];
        int nb = t * 16 + q * 4;
        z[PAD(nb + 0)] = make_float2(raw0[q * 4 + 0] * hw.x, raw1[q * 4 + 0] * hw.x);
        z[PAD(nb + 1)] = make_float2(raw0[q * 4 + 1] * hw.y, raw1[q * 4 + 1] * hw.y);
        z[PAD(nb + 2)] = make_float2(raw0[q * 4 + 2] * hw.z, raw1[q * 4 + 2] * hw.z);
        z[PAD(nb + 3)] = make_float2(raw0[q * 4 + 3] * hw.w, raw1[q * 4 + 3] * hw.w);
    }

    // ---- local branch in registers (2 windows of 8 per thread, both lines) ----
    float alc = gate[b * 8 + h];
    const float* alb = al + b * 80;
    float effl_f[5], effl_b[5];
    #pragma unroll
    for (int f = 0; f < 5; ++f) {
        int idx = h * 5 + f;
        effl_f[f] = bf_l[idx] * (1.0f + alb[idx * 2]);
        effl_b[f] = bb_l[idx] + alb[idx * 2 + 1];
    }
    const float s8 = 0.3535533905932738f;  // 1/sqrt(8)
    const float c7 = 0.7071067811865476f;
    const float cosT[8] = {1.f, c7, 0.f, -c7, -1.f, -c7, 0.f, c7};
    const float sinT[8] = {0.f, c7, 1.f, c7, 0.f, -c7, -1.f, -c7};
    const float hl[8] = {0.f, 0.18825510f, 0.61126047f, 0.95048444f,
                         0.95048444f, 0.61126047f, 0.18825510f, 0.f};
    float xl0[16], xl1[16];
    #pragma unroll
    for (int ln = 0; ln < 2; ++ln) {
        float* rawp = ln ? raw1 : raw0;
        float* xlp  = ln ? xl1 : xl0;
        #pragma unroll
        for (int w2 = 0; w2 < 2; ++w2) {
            float xw[8];
            #pragma unroll
            for (int j = 0; j < 8; ++j) xw[j] = rawp[w2 * 8 + j] * hl[j];
            float Yr[5], Yi[5];
            #pragma unroll
            for (int f = 0; f < 5; ++f) {
                float fr = 0.f, fi = 0.f;
                #pragma unroll
                for (int j = 0; j < 8; ++j) {
                    int k8 = (f * j) & 7;
                    fr += xw[j] * cosT[k8];
                    fi -= xw[j] * sinT[k8];
                }
                fr *= s8; fi *= s8;
                float zr = fr * effl_f[f] + effl_b[f];
                float zi = fi * effl_f[f];
                float mag = sqrtf(zr * zr + zi * zi);
                float g = gelu_f(mag) * __builtin_amdgcn_rcpf(mag + 1e-6f);
                Yr[f] = zr * g; Yi[f] = zi * g;
            }
            #pragma unroll
            for (int j = 0; j < 8; ++j) {
                float acc = Yr[0] + Yr[4] * ((j & 1) ? -1.f : 1.f);
                #pragma unroll
                for (int f = 1; f < 4; ++f) {
                    int k8 = (f * j) & 7;
                    acc += 2.f * (Yr[f] * cosT[k8] - Yi[f] * sinT[k8]);
                }
                xlp[w2 * 8 + j] = acc * s8;
            }
        }
    }

    __syncthreads();
    // ---- forward DIF: LDS stages Q=1024,256,64,16, then 16-pt in registers ----
    dif_stage<10>(z, twg, t); __syncthreads();
    dif_stage<8>(z, twg, t);  __syncthreads();
    dif_stage<6>(z, twg, t);  __syncthreads();
    dif_stage<4>(z, twg, t);  __syncthreads();
    {
        float2 v[16];
        #pragma unroll
        for (int i = 0; i < 16; ++i) v[i] = z[PAD(t * 16 + i)];
        fwd16(v);
        #pragma unroll
        for (int i = 0; i < 16; ++i) z[PAD(t * 16 + i)] = v[i];
    }
    __syncthreads();

    // Hermitian split + modulate + cgelu + re-pack, bin k at position rev4(k)
    const float inv64 = 1.0f / 64.0f;
    const float* agb = ag + (size_t)b * 32784;
    for (int k = t; k < 2048; k += 256) {
        int km = (4096 - k) & 4095;
        int pk = PAD(rev4_12(k)), pm = PAD(rev4_12(km));
        float2 Z = z[pk], Z2 = z[pm];
        float X0r = 0.5f * (Z.x + Z2.x), X0i = 0.5f * (Z.y - Z2.y);
        float X1r = 0.5f * (Z.y + Z2.y), X1i = -0.5f * (Z.x - Z2.x);
        int idx = h * FG_ + k;
        float efff = bf_g[idx] * (1.0f + agb[idx * 2]);
        float effb = bb_g[idx] + agb[idx * 2 + 1];
        float z0r = X0r * inv64 * efff + effb, z0i = X0i * inv64 * efff;
        float m0 = sqrtf(z0r * z0r + z0i * z0i);
        float g0 = gelu_f(m0) * __builtin_amdgcn_rcpf(m0 + 1e-6f);
        float Y0r = z0r * g0, Y0i = z0i * g0;
        float z1r = X1r * inv64 * efff + effb, z1i = X1i * inv64 * efff;
        float m1 = sqrtf(z1r * z1r + z1i * z1i);
        float g1 = gelu_f(m1) * __builtin_amdgcn_rcpf(m1 + 1e-6f);
        float Y1r = z1r * g1, Y1i = z1i * g1;
        z[pk] = make_float2(Y0r - Y1i, Y0i + Y1r);
        if (k) z[pm] = make_float2(Y0r + Y1i, Y1r - Y0i);
    }
    if (t == 0) {  // Nyquist bin k=2048 (self-mirror; X0,X1 real)
        int pk = PAD(rev4_12(2048));
        float2 Z = z[pk];
        int idx = h * FG_ + 2048;
        float efff = bf_g[idx] * (1.0f + agb[idx * 2]);
        float effb = bb_g[idx] + agb[idx * 2 + 1];
        float z0r = Z.x * inv64 * efff + effb;
        float m0 = fabsf(z0r);
        float Y0r = z0r * (gelu_f(m0) * __builtin_amdgcn_rcpf(m0 + 1e-6f));
        float z1r = Z.y * inv64 * efff + effb;
        float m1 = fabsf(z1r);
        float Y1r = z1r * (gelu_f(m1) * __builtin_amdgcn_rcpf(m1 + 1e-6f));
        z[pk] = make_float2(Y0r, Y1r);
    }
    __syncthreads();

    // ---- inverse DIT: 16-pt in registers, then LDS stages Q=16,64,256,1024 ----
    {
        float2 v[16];
        #pragma unroll
        for (int i = 0; i < 16; ++i) v[i] = z[PAD(t * 16 + i)];
        inv16(v);
        #pragma unroll
        for (int i = 0; i < 16; ++i) z[PAD(t * 16 + i)] = v[i];
    }
    __syncthreads();
    dit_stage<4>(z, twg, t);  __syncthreads();
    dit_stage<6>(z, twg, t);  __syncthreads();
    dit_stage<8>(z, twg, t);  __syncthreads();
    dit_stage<10>(z, twg, t); __syncthreads();

    // fuse and store both lines (natural order)
    float* dst0 = fused + (size_t)line0 * N_;
    float* dst1 = dst0 + N_;
    float one_m = 1.0f - alc;
    #pragma unroll
    for (int q = 0; q < 4; ++q) {
        int base = t * 16 + q * 4;
        float2 za = z[PAD(base + 0)], zb = z[PAD(base + 1)];
        float2 zc = z[PAD(base + 2)], zd = z[PAD(base + 3)];
        float4 v0 = make_float4(alc * za.x * inv64 + one_m * xl0[q * 4 + 0],
                                alc * zb.x * inv64 + one_m * xl0[q * 4 + 1],
                                alc * zc.x * inv64 + one_m * xl0[q * 4 + 2],
                                alc * zd.x * inv64 + one_m * xl0[q * 4 + 3]);
        float4 v1 = make_float4(alc * za.y * inv64 + one_m * xl1[q * 4 + 0],
                                alc * zb.y * inv64 + one_m * xl1[q * 4 + 1],
                                alc * zc.y * inv64 + one_m * xl1[q * 4 + 2],
                                alc * zd.y * inv64 + one_m * xl1[q * 4 + 3]);
        ((float4*)dst0)[t * 4 + q] = v0;
        ((float4*)dst1)[t * 4 + q] = v1;
    }
}

// out[b,n,d] = x[b,n,d] + fused[b,d,n]  (tiled transpose-add)
__global__ void k_addout(const float* __restrict__ fused, const float* __restrict__ x,
                         float* __restrict__ out) {
    __shared__ float tile[64][65];
    int d0 = blockIdx.x * 64, n0 = blockIdx.y * 64, b = blockIdx.z;
    int c = threadIdx.x & 63, r4 = threadIdx.x >> 6;
    for (int q = 0; q < 16; ++q) {
        int r = r4 * 16 + q;  // d-row
        tile[r][c] = fused[((size_t)b * D_ + d0 + r) * N_ + n0 + c];
    }
    __syncthreads();
    for (int q = 0; q < 16; ++q) {
        int r = r4 * 16 + q;  // n-row
        size_t o = ((size_t)b * N_ + n0 + r) * D_ + d0 + c;
        out[o] = x[o] + tile[c][r];
    }
}

extern "C" void kernel_launch(void* const* d_in, const int* in_sizes, int n_in,
                              void* d_out, int out_size, void* d_ws, size_t ws_size,
                              hipStream_t stream) {
    const float* x    = (const float*)d_in[0];
    const float* ln_w = (const float*)d_in[1];
    const float* ln_b = (const float*)d_in[2];
    const float* bf_g = (const float*)d_in[3];
    const float* bb_g = (const float*)d_in[4];
    const float* bf_l = (const float*)d_in[5];
    const float* bb_l = (const float*)d_in[6];
    const float* w1g  = (const float*)d_in[7];
    const float* b1g  = (const float*)d_in[8];
    const float* w2g  = (const float*)d_in[9];
    const float* b2g  = (const float*)d_in[10];
    const float* w1l  = (const float*)d_in[11];
    const float* b1l  = (const float*)d_in[12];
    const float* w2l  = (const float*)d_in[13];
    const float* b2l  = (const float*)d_in[14];
    const float* wf1  = (const float*)d_in[15];
    const float* bf1  = (const float*)d_in[16];
    const float* wf2  = (const float*)d_in[17];
    const float* bf2  = (const float*)d_in[18];
    float* out = (float*)d_out;

    char* ws = (char*)d_ws;
    const size_t big = (size_t)B_ * D_ * N_ * sizeof(float);  // ~100.7 MB
    float* XT  = (float*)ws; ws += big;
    float* FU  = (float*)ws; ws += big;   // fused output of spectral
    float* ctx = (float*)ws; ws += (size_t)B_ * D_ * 4;
    float* h1g = (float*)ws; ws += (size_t)B_ * 768 * 4;
    float* h1l = (float*)ws; ws += (size_t)B_ * 768 * 4;
    float* hf  = (float*)ws; ws += (size_t)B_ * 384 * 4;
    float* ag  = (float*)ws; ws += (size_t)B_ * 32784 * 4;
    float* alb = (float*)ws; ws += (size_t)B_ * 80 * 4;
    float* gat = (float*)ws; ws += (size_t)B_ * 8 * 4;
    float2* twg = (float2*)ws; ws += 2048 * sizeof(float2);
    float* hanng = (float*)ws; ws += 4096 * sizeof(float);
    // mu/rstd alias the head of FU: dead before k_spectral writes FU.
    float* mu   = FU;
    float* rstd = FU + 32768;

    k_init<<<129, 256, 0, stream>>>(b2g, b2l, twg, hanng, ctx, ag, alb);
    k_stats<<<8192, 256, 0, stream>>>(x, mu, rstd);
    k_lnT<<<dim3(12, 64, 8), 256, 0, stream>>>(x, mu, rstd, ln_w, ln_b, XT, ctx);
    k_mlp1<<<8, 256, 0, stream>>>(ctx, w1g, b1g, w1l, b1l, wf1, bf1, h1g, h1l, hf);
    k_mlp2<<<dim3(129, 8), 256, 0, stream>>>(h1g, h1l, hf, w2g, w2l, wf2, bf2, ag, alb, gat);
    k_spectral<<<B_ * D_ / 2, 256, 0, stream>>>(XT, ag, alb, gat, bf_g, bb_g, bf_l, bb_l,
                                                twg, hanng, FU);
    k_addout<<<dim3(12, 64, 8), 256, 0, stream>>>(FU, x, out);
}